// Round 2
// baseline (23694.992 us; speedup 1.0000x reference)
//
#include <hip/hip_runtime.h>
#include <stdint.h>

#define B_  16
#define T_  2048
#define D_  512

typedef short v8s __attribute__((ext_vector_type(8)));
typedef float v4f __attribute__((ext_vector_type(4)));

// ws layout (bytes)
#define WT_OFF    0u           // 8 MB  bf16 weight fragments (2 layer x 2 mat x 512 x 2048)
#define H0_OFF    8388608u     // 32 MB h0[t][b][d] bf16
#define H1_OFF    41943040u    // 32 MB h1[t][b][d] bf16
#define FLAGS_OFF 75497472u    // 128 ints (flags0[64], flags1[64]), padded to 4KB
#define XB_OFF    75501568u    // 32 MB x_bf16[t][b][d] (optional)
#define WS_NEED_FULL (XB_OFF + 33554432u)

__device__ __forceinline__ short f2bf(float f) {
  unsigned u = __builtin_bit_cast(unsigned, f);
  u = (u + 0x7FFFu + ((u >> 16) & 1u)) >> 16;
  return (short)u;
}

__device__ __forceinline__ float sigmoid_fast(float z) {
  return 1.f / (1.f + __expf(-z));
}
__device__ __forceinline__ float tanh_fast(float z) {
  float e = __expf(2.f * z);
  return 1.f - 2.f / (e + 1.f);
}

// Transpose Wx/Wh (fp32 [L][512][2048]) into bf16 MFMA B-fragment layout:
// wT[(((l*2+mat)*64+g)*2+ntile)*16+kap][lane][j]  with
//   lane = quad*16+n,  B[k=kap*32+quad*8+j][col= 512*q + g*8 + jj], c=q*8+jj=ntile*16+n
__global__ void prep_weights(const float* __restrict__ Wx, const float* __restrict__ Wh,
                             short* __restrict__ wT, int* __restrict__ flags) {
  int tid = blockIdx.x * 256 + threadIdx.x;            // [0, 2^22)
  if (blockIdx.x == 0 && threadIdx.x < 128) flags[threadIdx.x] = 0;
  int l   = tid >> 21;
  int mat = (tid >> 20) & 1;
  int rem = tid & ((1 << 20) - 1);
  int k   = rem >> 11;
  int col = rem & 2047;
  const float* src = mat ? Wh : Wx;
  float v = src[(l << 20) + (k << 11) + col];
  int q = col >> 9, r9 = col & 511, g = r9 >> 3, jj = r9 & 7;
  int c = q * 8 + jj, ntile = c >> 4, n = c & 15;
  int kap = k >> 5, k5 = k & 31, quad = k5 >> 3, j = k5 & 7;
  int lane = quad * 16 + n;
  int dst = ((((l * 2 + mat) * 64 + g) * 2 + ntile) * 16 + kap) * 512 + lane * 8 + j;
  wT[dst] = f2bf(v);
}

// x [b][t][d] fp32  ->  xb [t][b][d] bf16
__global__ void prep_x(const float* __restrict__ x, short* __restrict__ xb) {
  int tid = blockIdx.x * 256 + threadIdx.x;            // [0, 2^24)
  int b = tid >> 20, r = tid & ((1 << 20) - 1), t = r >> 9, d = r & 511;
  xb[((t * 16 + b) << 9) + d] = f2bf(x[tid]);
}

template <bool XBF16>
__global__ __launch_bounds__(256, 1) void lstm_persist(
    const float* __restrict__ x, const short* __restrict__ xb,
    const short* __restrict__ wT, const float* __restrict__ bias,
    short* h0, short* h1, int* flags, float* __restrict__ out) {
  const int wg   = blockIdx.x;
  const int l    = wg >> 6;       // layer 0 or 1
  const int g    = wg & 63;       // column group
  const int tid  = threadIdx.x;
  const int wave = tid >> 6;
  const int lane = tid & 63;
  const int mat  = wave >> 1;     // 0 = input kernel (Wx), 1 = recurrent (Wh)
  const int ntile = wave & 1;
  const int n15  = lane & 15;
  const int quad = lane >> 4;

  // pad 36: LDSG write bank = (16*quad+4*r+n15)%32 -> 2-way (free, m136);
  // epilogue read bank = (4*bb+8*q+jj)%32 -> 2-way.
  __shared__ float LDSG[2][16][36];
  // weights staged once in LDS: immune to per-step L2 invalidation, and the
  // compiler can't demote these to per-step global reloads (the R1 bug:
  // VGPR=52 proved bfrag[16] was rematerialized from global every step).
  __shared__ short WLDS[4][16][512];   // 64 KB: [wave][kk][lane*8+j]

  int* flags0 = flags;
  int* flags1 = flags + 64;
  int* flagsOwn = l ? flags1 : flags0;
  short* hOwn = l ? h1 : h0;

  // stage loop-invariant B fragments -> LDS (once)
  {
    const short* wb = wT + (size_t)((((l * 2 + mat) * 64 + g) * 2 + ntile) * 16) * 512;
#pragma unroll
    for (int kk = 0; kk < 16; ++kk)
      *(v8s*)&WLDS[wave][kk][lane * 8] = *(const v8s*)(wb + kk * 512 + lane * 8);
  }
  __syncthreads();

  // per-thread epilogue state (tid < 128): thread -> (batch bb, col jj)
  const int bb = tid >> 3, jj = tid & 7;
  const int colg = g * 8 + jj;                       // d index in [0,512)
  float bq[4];
#pragma unroll
  for (int q = 0; q < 4; ++q) bq[q] = bias[l * 2048 + q * 512 + colg];
  float c_state = 0.f;
  const size_t xTB = (size_t)bb * T_ * D_ + colg;    // x[bb][t][colg] base (add t*512)

  for (int t = 0; t < T_; ++t) {
    // ---------- wait for inputs (every wave polls; no barrier needed) ----------
    const bool needPoll = (l == 1) || (t > 0);
    if (needPoll) {
      for (;;) {
        bool p;
        if (l == 0) {
          int f = __hip_atomic_load(&flags0[lane], __ATOMIC_RELAXED, __HIP_MEMORY_SCOPE_AGENT);
          p = (f >= t);
        } else {
          int fp = __hip_atomic_load(&flags0[lane], __ATOMIC_RELAXED, __HIP_MEMORY_SCOPE_AGENT);
          p = (fp >= t + 1);
          if (t > 0) {
            int fo = __hip_atomic_load(&flags1[lane], __ATOMIC_RELAXED, __HIP_MEMORY_SCOPE_AGENT);
            p = p && (fo >= t);
          }
        }
        if (__ballot(p) == 0xFFFFFFFFFFFFFFFFull) break;
        __builtin_amdgcn_s_sleep(1);
      }
      __builtin_amdgcn_fence(__ATOMIC_ACQUIRE, "agent");
    }

    // ---------- MFMA: this wave's 16-col tile of (A @ Wmat) ----------
    v4f acc = {0.f, 0.f, 0.f, 0.f};
    const bool doIt = (mat == 0) || (t > 0);
    if (doIt) {
      if (!XBF16 && mat == 0 && l == 0) {
        const float* A = x + (size_t)(n15 * T_ + t) * D_ + quad * 8;
#pragma unroll
        for (int kk = 0; kk < 16; ++kk) {
          float4 f0 = *(const float4*)(A + kk * 32);
          float4 f1 = *(const float4*)(A + kk * 32 + 4);
          v8s a;
          a[0] = f2bf(f0.x); a[1] = f2bf(f0.y); a[2] = f2bf(f0.z); a[3] = f2bf(f0.w);
          a[4] = f2bf(f1.x); a[5] = f2bf(f1.y); a[6] = f2bf(f1.z); a[7] = f2bf(f1.w);
          v8s bf = *(const v8s*)&WLDS[wave][kk][lane * 8];
          acc = __builtin_amdgcn_mfma_f32_16x16x32_bf16(a, bf, acc, 0, 0, 0);
        }
      } else {
        const short* A;
        if (mat == 0) {
          A = (l == 0) ? (xb + ((size_t)(t * 16 + n15) << 9) + quad * 8)
                       : (h0 + ((size_t)(t * 16 + n15) << 9) + quad * 8);
        } else {
          A = hOwn + ((size_t)((t - 1) * 16 + n15) << 9) + quad * 8;
        }
#pragma unroll
        for (int kk = 0; kk < 16; ++kk) {
          v8s a = *(const v8s*)(A + kk * 32);
          v8s bf = *(const v8s*)&WLDS[wave][kk][lane * 8];
          acc = __builtin_amdgcn_mfma_f32_16x16x32_bf16(a, bf, acc, 0, 0, 0);
        }
      }
    }
    {
      const int rb = quad * 4;
#pragma unroll
      for (int r = 0; r < 4; ++r)
        LDSG[mat][rb + r][ntile * 16 + n15] = acc[r];
    }
    __syncthreads();

    // ---------- epilogue: gates -> (c,h) ----------
    if (tid < 128) {
      float pa[4];
#pragma unroll
      for (int q = 0; q < 4; ++q)
        pa[q] = LDSG[0][bb][q * 8 + jj] + LDSG[1][bb][q * 8 + jj] + bq[q];
      float ig = sigmoid_fast(pa[0]);
      float fg = sigmoid_fast(pa[1]);
      float gg = tanh_fast(pa[2]);
      float og = sigmoid_fast(pa[3]);
      c_state = fg * c_state + ig * gg;
      float h = og * tanh_fast(c_state);
      hOwn[((size_t)(t * 16 + bb) << 9) + colg] = f2bf(h);
      if (l == 1) {
        size_t xi = xTB + (size_t)t * D_;
        out[xi] = h + x[xi];
      }
    }
    __syncthreads();
    if (tid == 0) {
      __builtin_amdgcn_fence(__ATOMIC_RELEASE, "agent");
      __hip_atomic_store(&flagsOwn[g], t + 1, __ATOMIC_RELAXED, __HIP_MEMORY_SCOPE_AGENT);
    }
  }
}

extern "C" void kernel_launch(void* const* d_in, const int* in_sizes, int n_in,
                              void* d_out, int out_size, void* d_ws, size_t ws_size,
                              hipStream_t stream) {
  const float* x    = (const float*)d_in[0];
  const float* Wx   = (const float*)d_in[1];
  const float* Wh   = (const float*)d_in[2];
  const float* bias = (const float*)d_in[3];
  float* out = (float*)d_out;

  char* ws   = (char*)d_ws;
  short* wT  = (short*)(ws + WT_OFF);
  short* h0  = (short*)(ws + H0_OFF);
  short* h1  = (short*)(ws + H1_OFF);
  int* flags = (int*)(ws + FLAGS_OFF);
  short* xb  = (short*)(ws + XB_OFF);

  const bool xbf16 = (ws_size >= (size_t)WS_NEED_FULL);

  hipLaunchKernelGGL(prep_weights, dim3(16384), dim3(256), 0, stream, Wx, Wh, wT, flags);
  if (xbf16) {
    hipLaunchKernelGGL(prep_x, dim3(65536), dim3(256), 0, stream, x, xb);
    hipLaunchKernelGGL((lstm_persist<true>), dim3(128), dim3(256), 0, stream,
                       x, xb, wT, bias, h0, h1, flags, out);
  } else {
    hipLaunchKernelGGL((lstm_persist<false>), dim3(128), dim3(256), 0, stream,
                       x, xb, wT, bias, h0, h1, flags, out);
  }
}

// Round 3
// 21149.104 us; speedup vs baseline: 1.1204x; 1.1204x over previous
//
#include <hip/hip_runtime.h>
#include <stdint.h>

#define B_  16
#define T_  2048
#define D_  512

typedef short v8s __attribute__((ext_vector_type(8)));
typedef float v4f __attribute__((ext_vector_type(4)));
typedef int   v4i __attribute__((ext_vector_type(4)));

// ws layout (bytes)
#define WT_OFF    0u           // 8 MB  bf16 weight fragments (2 layer x 2 mat x 512 x 2048)
#define H0_OFF    8388608u     // 32 MB h0[t][b][d] bf16
#define H1_OFF    41943040u    // 32 MB h1[t][b][d] bf16
#define FLAGS_OFF 75497472u    // 128 ints (flags0[64], flags1[64]), padded to 4KB
#define XB_OFF    75501568u    // 32 MB x_bf16[t][b][d] (optional)
#define WS_NEED_FULL (XB_OFF + 33554432u)

__device__ __forceinline__ short f2bf(float f) {
  unsigned u = __builtin_bit_cast(unsigned, f);
  u = (u + 0x7FFFu + ((u >> 16) & 1u)) >> 16;
  return (short)u;
}

__device__ __forceinline__ float sigmoid_fast(float z) {
  return 1.f / (1.f + __expf(-z));
}
__device__ __forceinline__ float tanh_fast(float z) {
  float e = __expf(2.f * z);
  return 1.f - 2.f / (e + 1.f);
}

__device__ __forceinline__ int cohLoad(const int* p) {
  return __hip_atomic_load((int*)p, __ATOMIC_RELAXED, __HIP_MEMORY_SCOPE_AGENT);
}
__device__ __forceinline__ void cohStore(int* p, int v) {
  __hip_atomic_store(p, v, __ATOMIC_RELAXED, __HIP_MEMORY_SCOPE_AGENT);
}

// Transpose Wx/Wh (fp32 [L][512][2048]) into bf16 MFMA B-fragment layout:
// wT[(((l*2+mat)*64+g)*2+ntile)*16+kap][lane][j]  with
//   lane = quad*16+n,  B[k=kap*32+quad*8+j][col= 512*q + g*8 + jj], c=q*8+jj=ntile*16+n
__global__ void prep_weights(const float* __restrict__ Wx, const float* __restrict__ Wh,
                             short* __restrict__ wT, int* __restrict__ flags) {
  int tid = blockIdx.x * 256 + threadIdx.x;            // [0, 2^22)
  if (blockIdx.x == 0 && threadIdx.x < 128) flags[threadIdx.x] = 0;
  int l   = tid >> 21;
  int mat = (tid >> 20) & 1;
  int rem = tid & ((1 << 20) - 1);
  int k   = rem >> 11;
  int col = rem & 2047;
  const float* src = mat ? Wh : Wx;
  float v = src[(l << 20) + (k << 11) + col];
  int q = col >> 9, r9 = col & 511, g = r9 >> 3, jj = r9 & 7;
  int c = q * 8 + jj, ntile = c >> 4, n = c & 15;
  int kap = k >> 5, k5 = k & 31, quad = k5 >> 3, j = k5 & 7;
  int lane = quad * 16 + n;
  int dst = ((((l * 2 + mat) * 64 + g) * 2 + ntile) * 16 + kap) * 512 + lane * 8 + j;
  wT[dst] = f2bf(v);
}

// x [b][t][d] fp32  ->  xb [t][b][d] bf16
__global__ void prep_x(const float* __restrict__ x, short* __restrict__ xb) {
  int tid = blockIdx.x * 256 + threadIdx.x;            // [0, 2^24)
  int b = tid >> 20, r = tid & ((1 << 20) - 1), t = r >> 9, d = r & 511;
  xb[((t * 16 + b) << 9) + d] = f2bf(x[tid]);
}

template <bool XBF16>
__global__ __launch_bounds__(256, 1) void lstm_persist(
    const float* __restrict__ x, const short* __restrict__ xb,
    const short* __restrict__ wT, const float* __restrict__ bias,
    short* h0, short* h1, int* flags, float* __restrict__ out) {
  const int wg   = blockIdx.x;
  const int l    = wg >> 6;       // layer 0 or 1
  const int g    = wg & 63;       // column group
  const int tid  = threadIdx.x;
  const int wave = tid >> 6;
  const int lane = tid & 63;
  const int mat  = wave >> 1;     // 0 = input kernel (Wx), 1 = recurrent (Wh)
  const int ntile = wave & 1;
  const int n15  = lane & 15;
  const int quad = lane >> 4;

  // pad 36: LDSG write bank = (16*quad+4*r+n15)%32 -> 2-way (free, m136)
  __shared__ float LDSG[2][16][36];
  // weights staged once in LDS (keeps them out of the per-step global path)
  __shared__ short WLDS[4][16][512];   // 64 KB: [wave][kk][lane*8+j]
  __shared__ short HOUT[16][8];        // this WG's h slice, packed for coherent stores

  int* flags0 = flags;
  int* flags1 = flags + 64;
  int* flagsOwn = l ? flags1 : flags0;
  short* hOwn = l ? h1 : h0;

  // stage loop-invariant B fragments -> LDS (once)
  {
    const short* wb = wT + (size_t)((((l * 2 + mat) * 64 + g) * 2 + ntile) * 16) * 512;
#pragma unroll
    for (int kk = 0; kk < 16; ++kk)
      *(v8s*)&WLDS[wave][kk][lane * 8] = *(const v8s*)(wb + kk * 512 + lane * 8);
  }
  __syncthreads();

  // per-thread epilogue state (tid < 128): thread -> (batch bb, col jj)
  const int bb = tid >> 3, jj = tid & 7;
  const int colg = g * 8 + jj;                       // d index in [0,512)
  float bq[4];
#pragma unroll
  for (int q = 0; q < 4; ++q) bq[q] = bias[l * 2048 + q * 512 + colg];
  float c_state = 0.f;
  const size_t xTB = (size_t)bb * T_ * D_ + colg;    // x[bb][t][colg] base (add t*512)

  for (int t = 0; t < T_; ++t) {
    // ---------- wait for inputs: wave0 polls coherent flags; NO fences ----------
    const bool needPoll = (l == 1) || (t > 0);
    if (needPoll) {
      if (wave == 0) {
        for (;;) {
          bool p;
          if (l == 0) {
            p = (cohLoad(&flags0[lane]) >= t);
          } else {
            p = (cohLoad(&flags0[lane]) >= t + 1);
            if (t > 0) p = p && (cohLoad(&flags1[lane]) >= t);
          }
          if (__ballot(p) == 0xFFFFFFFFFFFFFFFFull) break;
          __builtin_amdgcn_s_sleep(1);
        }
      }
      __syncthreads();
    }

    // ---------- MFMA: this wave's 16-col tile of (A @ Wmat) ----------
    v4f acc = {0.f, 0.f, 0.f, 0.f};
    const bool doIt = (mat == 0) || (t > 0);
    if (doIt) {
      if (mat == 0 && l == 0) {
        if (XBF16) {
          const short* A = xb + ((size_t)(t * 16 + n15) << 9) + quad * 8;
#pragma unroll
          for (int kk = 0; kk < 16; ++kk) {
            v8s a = *(const v8s*)(A + kk * 32);
            v8s bf = *(const v8s*)&WLDS[wave][kk][lane * 8];
            acc = __builtin_amdgcn_mfma_f32_16x16x32_bf16(a, bf, acc, 0, 0, 0);
          }
        } else {
          const float* A = x + (size_t)(n15 * T_ + t) * D_ + quad * 8;
#pragma unroll
          for (int kk = 0; kk < 16; ++kk) {
            float4 f0 = *(const float4*)(A + kk * 32);
            float4 f1 = *(const float4*)(A + kk * 32 + 4);
            v8s a;
            a[0] = f2bf(f0.x); a[1] = f2bf(f0.y); a[2] = f2bf(f0.z); a[3] = f2bf(f0.w);
            a[4] = f2bf(f1.x); a[5] = f2bf(f1.y); a[6] = f2bf(f1.z); a[7] = f2bf(f1.w);
            v8s bf = *(const v8s*)&WLDS[wave][kk][lane * 8];
            acc = __builtin_amdgcn_mfma_f32_16x16x32_bf16(a, bf, acc, 0, 0, 0);
          }
        }
      } else {
        // coherent (sc1) A loads: h written by other WGs, read once, fence-free.
        const short* Abase = (mat == 0)
            ? (h0 + ((size_t)(t * 16 + n15) << 9) + quad * 8)        // l1 input: h0[t]
            : (hOwn + ((size_t)((t - 1) * 16 + n15) << 9) + quad * 8); // recurrent: h[t-1]
        const int* Ai = (const int*)Abase;
        v8s afr[16];
#pragma unroll
        for (int kk = 0; kk < 16; ++kk) {
          v4i w;
#pragma unroll
          for (int c = 0; c < 4; ++c)
            w[c] = cohLoad(Ai + kk * 16 + c);
          afr[kk] = __builtin_bit_cast(v8s, w);
        }
#pragma unroll
        for (int kk = 0; kk < 16; ++kk) {
          v8s bf = *(const v8s*)&WLDS[wave][kk][lane * 8];
          acc = __builtin_amdgcn_mfma_f32_16x16x32_bf16(afr[kk], bf, acc, 0, 0, 0);
        }
      }
    }
    {
      const int rb = quad * 4;
#pragma unroll
      for (int r = 0; r < 4; ++r)
        LDSG[mat][rb + r][ntile * 16 + n15] = acc[r];
    }
    __syncthreads();

    // ---------- epilogue: gates -> (c,h) ----------
    if (tid < 128) {
      float pa[4];
#pragma unroll
      for (int q = 0; q < 4; ++q)
        pa[q] = LDSG[0][bb][q * 8 + jj] + LDSG[1][bb][q * 8 + jj] + bq[q];
      float ig = sigmoid_fast(pa[0]);
      float fg = sigmoid_fast(pa[1]);
      float gg = tanh_fast(pa[2]);
      float og = sigmoid_fast(pa[3]);
      c_state = fg * c_state + ig * gg;
      float h = og * tanh_fast(c_state);
      HOUT[bb][jj] = f2bf(h);
      if (l == 1) {
        size_t xi = xTB + (size_t)t * D_;
        out[xi] = h + x[xi];
      }
    }
    __syncthreads();

    // ---------- publish h slice + flag (wave0 only; per-wave vmcnt ordering) ----------
    if (wave == 0) {
      const int b_ = lane >> 2, pr = lane & 3;
      int val = *(const int*)&HOUT[b_][pr * 2];
      cohStore((int*)(hOwn + ((size_t)(t * 16 + b_) << 9) + g * 8 + pr * 2), val);
      asm volatile("" ::: "memory");
      __builtin_amdgcn_s_waitcnt(0);   // drain wave0's h stores to the LLC
      asm volatile("" ::: "memory");
      if (lane == 0)
        cohStore(&flagsOwn[g], t + 1);
    }
  }
}

extern "C" void kernel_launch(void* const* d_in, const int* in_sizes, int n_in,
                              void* d_out, int out_size, void* d_ws, size_t ws_size,
                              hipStream_t stream) {
  const float* x    = (const float*)d_in[0];
  const float* Wx   = (const float*)d_in[1];
  const float* Wh   = (const float*)d_in[2];
  const float* bias = (const float*)d_in[3];
  float* out = (float*)d_out;

  char* ws   = (char*)d_ws;
  short* wT  = (short*)(ws + WT_OFF);
  short* h0  = (short*)(ws + H0_OFF);
  short* h1  = (short*)(ws + H1_OFF);
  int* flags = (int*)(ws + FLAGS_OFF);
  short* xb  = (short*)(ws + XB_OFF);

  const bool xbf16 = (ws_size >= (size_t)WS_NEED_FULL);

  hipLaunchKernelGGL(prep_weights, dim3(16384), dim3(256), 0, stream, Wx, Wh, wT, flags);
  if (xbf16) {
    hipLaunchKernelGGL(prep_x, dim3(65536), dim3(256), 0, stream, x, xb);
    hipLaunchKernelGGL((lstm_persist<true>), dim3(128), dim3(256), 0, stream,
                       x, xb, wT, bias, h0, h1, flags, out);
  } else {
    hipLaunchKernelGGL((lstm_persist<false>), dim3(128), dim3(256), 0, stream,
                       x, xb, wT, bias, h0, h1, flags, out);
  }
}

// Round 4
// 7367.093 us; speedup vs baseline: 3.2163x; 2.8708x over previous
//
#include <hip/hip_runtime.h>
#include <stdint.h>

#define B_  16
#define T_  2048
#define D_  512

typedef short v8s __attribute__((ext_vector_type(8)));
typedef float v4f __attribute__((ext_vector_type(4)));

// ws layout (bytes)
#define WT_OFF    0u           // 8 MB  bf16 weight fragments
#define H0_OFF    8388608u     // 32 MB h0 packed [t][d/8][b][8] bf16
#define H1_OFF    41943040u    // 32 MB h1 packed
#define FLAGS_OFF 75497472u    // 128 ints (flags0[64], flags1[64])
#define XB_OFF    75501568u    // 32 MB x packed [t][d/8][b][8] bf16 (optional)
#define WS_NEED_FULL (XB_OFF + 33554432u)

__device__ __forceinline__ short f2bf(float f) {
  unsigned u = __builtin_bit_cast(unsigned, f);
  u = (u + 0x7FFFu + ((u >> 16) & 1u)) >> 16;
  return (short)u;
}
__device__ __forceinline__ float sigmoid_fast(float z) { return 1.f / (1.f + __expf(-z)); }
__device__ __forceinline__ float tanh_fast(float z) {
  float e = __expf(2.f * z);
  return 1.f - 2.f / (e + 1.f);
}
__device__ __forceinline__ int cohLoad(const int* p) {
  return __hip_atomic_load((int*)p, __ATOMIC_RELAXED, __HIP_MEMORY_SCOPE_AGENT);
}
__device__ __forceinline__ void cohStore(int* p, int v) {
  __hip_atomic_store(p, v, __ATOMIC_RELAXED, __HIP_MEMORY_SCOPE_AGENT);
}

// Wx/Wh fp32 [L][512][2048] -> bf16 MFMA B-fragment order (unchanged, validated R1-R3)
__global__ void prep_weights(const float* __restrict__ Wx, const float* __restrict__ Wh,
                             short* __restrict__ wT, int* __restrict__ flags) {
  int tid = blockIdx.x * 256 + threadIdx.x;            // [0, 2^22)
  if (blockIdx.x == 0 && threadIdx.x < 128) flags[threadIdx.x] = 0;
  int l   = tid >> 21;
  int mat = (tid >> 20) & 1;
  int rem = tid & ((1 << 20) - 1);
  int k   = rem >> 11;
  int col = rem & 2047;
  const float* src = mat ? Wh : Wx;
  float v = src[(l << 20) + (k << 11) + col];
  int q = col >> 9, r9 = col & 511, g = r9 >> 3, jj = r9 & 7;
  int c = q * 8 + jj, ntile = c >> 4, n = c & 15;
  int kap = k >> 5, k5 = k & 31, quad = k5 >> 3, j = k5 & 7;
  int lane = quad * 16 + n;
  int dst = ((((l * 2 + mat) * 64 + g) * 2 + ntile) * 16 + kap) * 512 + lane * 8 + j;
  wT[dst] = f2bf(v);
}

// x [b][t][d] fp32 -> packed xP[t][d/8][b][d%8] bf16 (A-fragment-native layout)
__global__ void prep_x(const float* __restrict__ x, short* __restrict__ xP) {
  int tid = blockIdx.x * 256 + threadIdx.x;            // [0, 2^24)
  int b = tid >> 20, r = tid & ((1 << 20) - 1), t = r >> 9, d = r & 511;
  xP[(size_t)t * 8192 + (d >> 3) * 128 + b * 8 + (d & 7)] = f2bf(x[tid]);
}

template <bool XBF16>
__global__ __launch_bounds__(256, 1) void lstm_persist(
    const float* __restrict__ x, const short* __restrict__ xP,
    const short* __restrict__ wT, const float* __restrict__ bias,
    short* h0, short* h1, int* flags, float* __restrict__ out) {
  const int wg   = blockIdx.x;
  const int l    = wg >> 6;       // layer 0 or 1
  const int g    = wg & 63;       // column group (8 h-cols)
  const int tid  = threadIdx.x;
  const int wave = tid >> 6;
  const int lane = tid & 63;
  const int mat  = wave >> 1;     // 0 = input kernel, 1 = recurrent
  const int ntile = wave & 1;
  const int n15  = lane & 15;
  const int quad = lane >> 4;

  __shared__ float LDSG[2][16][36];   // pad 36 -> 2-way max (free, m136)
  __shared__ short WLDS[4][16][512];  // 64 KB weight fragments

  int* flags0 = flags;
  int* flags1 = flags + 64;
  int* flagsOwn = l ? flags1 : flags0;
  short* hOwnP = l ? h1 : h0;

  // stage loop-invariant B fragments -> LDS (once)
  {
    const short* wb = wT + (size_t)((((l * 2 + mat) * 64 + g) * 2 + ntile) * 16) * 512;
#pragma unroll
    for (int kk = 0; kk < 16; ++kk)
      *(v8s*)&WLDS[wave][kk][lane * 8] = *(const v8s*)(wb + kk * 512 + lane * 8);
  }
  __syncthreads();

  // wave0 epilogue state: lane -> (batch bb, col pair jp): cols g*8+2jp, +1
  const int bb = lane >> 2, jp = lane & 3;
  float bq[4][2];
#pragma unroll
  for (int q = 0; q < 4; ++q) {
    bq[q][0] = bias[l * 2048 + q * 512 + g * 8 + 2 * jp];
    bq[q][1] = bias[l * 2048 + q * 512 + g * 8 + 2 * jp + 1];
  }
  float c0 = 0.f, c1 = 0.f;

  // A-fragment lane offset within a 8192-elem t-slice (packed layout)
  const int aOff = quad * 128 + n15 * 8;

  for (int t = 0; t < T_; ++t) {
    // ---------- wave0 polls coherent flags ----------
    if (wave == 0 && (l == 1 || t > 0)) {
      for (;;) {
        bool p;
        if (l == 0) {
          p = (cohLoad(&flags0[lane]) >= t);
        } else {
          p = (cohLoad(&flags0[lane]) >= t + 1);
          if (t > 0) p = p && (cohLoad(&flags1[lane]) >= t);
        }
        if (__ballot(p) == 0xFFFFFFFFFFFFFFFFull) break;
        __builtin_amdgcn_s_sleep(1);
      }
    }
    __syncthreads();

    // ---------- MFMA: 16-col tile of (A @ Wmat), A-frags direct-coalesced ----------
    v4f acc = {0.f, 0.f, 0.f, 0.f};
    if (mat == 0) {
      if (l == 0) {
        if (XBF16) {
          const short* p = xP + (size_t)t * 8192 + aOff;
          v8s afr[16];
#pragma unroll
          for (int kk = 0; kk < 16; ++kk) afr[kk] = *(const v8s*)(p + kk * 512);
#pragma unroll
          for (int kk = 0; kk < 16; ++kk)
            acc = __builtin_amdgcn_mfma_f32_16x16x32_bf16(afr[kk], *(const v8s*)&WLDS[wave][kk][lane * 8], acc, 0, 0, 0);
        } else {
          const float* A = x + (size_t)(n15 * T_ + t) * D_ + quad * 8;
#pragma unroll
          for (int kk = 0; kk < 16; ++kk) {
            float4 f0 = *(const float4*)(A + kk * 32);
            float4 f1 = *(const float4*)(A + kk * 32 + 4);
            v8s a;
            a[0] = f2bf(f0.x); a[1] = f2bf(f0.y); a[2] = f2bf(f0.z); a[3] = f2bf(f0.w);
            a[4] = f2bf(f1.x); a[5] = f2bf(f1.y); a[6] = f2bf(f1.z); a[7] = f2bf(f1.w);
            acc = __builtin_amdgcn_mfma_f32_16x16x32_bf16(a, *(const v8s*)&WLDS[wave][kk][lane * 8], acc, 0, 0, 0);
          }
        }
      } else {
        const short* p = h0 + (size_t)t * 8192 + aOff;   // plain loads: L2-cacheable
        v8s afr[16];
#pragma unroll
        for (int kk = 0; kk < 16; ++kk) afr[kk] = *(const v8s*)(p + kk * 512);
#pragma unroll
        for (int kk = 0; kk < 16; ++kk)
          acc = __builtin_amdgcn_mfma_f32_16x16x32_bf16(afr[kk], *(const v8s*)&WLDS[wave][kk][lane * 8], acc, 0, 0, 0);
      }
    } else if (t > 0) {
      const short* p = hOwnP + (size_t)(t - 1) * 8192 + aOff;
      v8s afr[16];
#pragma unroll
      for (int kk = 0; kk < 16; ++kk) afr[kk] = *(const v8s*)(p + kk * 512);
#pragma unroll
      for (int kk = 0; kk < 16; ++kk)
        acc = __builtin_amdgcn_mfma_f32_16x16x32_bf16(afr[kk], *(const v8s*)&WLDS[wave][kk][lane * 8], acc, 0, 0, 0);
    }
    {
      const int rb = quad * 4;
#pragma unroll
      for (int r = 0; r < 4; ++r)
        LDSG[mat][rb + r][ntile * 16 + n15] = acc[r];
    }
    __syncthreads();

    // ---------- wave0-only epilogue: gates -> (c,h), publish, flag ----------
    if (wave == 0) {
      float2 s[4];
#pragma unroll
      for (int q = 0; q < 4; ++q) {
        float2 a0 = *(const float2*)&LDSG[0][bb][q * 8 + 2 * jp];
        float2 a1 = *(const float2*)&LDSG[1][bb][q * 8 + 2 * jp];
        s[q].x = a0.x + a1.x + bq[q][0];
        s[q].y = a0.y + a1.y + bq[q][1];
      }
      float i0 = sigmoid_fast(s[0].x), i1 = sigmoid_fast(s[0].y);
      float f0 = sigmoid_fast(s[1].x), f1 = sigmoid_fast(s[1].y);
      float g0 = tanh_fast(s[2].x),    g1 = tanh_fast(s[2].y);
      float o0 = sigmoid_fast(s[3].x), o1 = sigmoid_fast(s[3].y);
      c0 = f0 * c0 + i0 * g0;
      c1 = f1 * c1 + i1 * g1;
      float h0v = o0 * tanh_fast(c0);
      float h1v = o1 * tanh_fast(c1);
      unsigned pack = (unsigned)(unsigned short)f2bf(h0v) |
                      ((unsigned)(unsigned short)f2bf(h1v) << 16);
      // packed slice: one fully-coalesced 256B coherent store for the wave
      cohStore((int*)hOwnP + (size_t)t * 4096 + g * 64 + bb * 4 + jp, (int)pack);
      asm volatile("" ::: "memory");
      __builtin_amdgcn_s_waitcnt(0);   // drain h store to LLC
      asm volatile("" ::: "memory");
      if (lane == 0)
        cohStore(&flagsOwn[g], t + 1);
      if (l == 1) {                    // residual output, after the flag (off critical path)
        size_t xi = (size_t)bb * T_ * D_ + (size_t)t * D_ + g * 8 + 2 * jp;
        float2 xv = *(const float2*)(x + xi);
        float2 ov; ov.x = h0v + xv.x; ov.y = h1v + xv.y;
        *(float2*)(out + xi) = ov;
      }
    }
  }
}

extern "C" void kernel_launch(void* const* d_in, const int* in_sizes, int n_in,
                              void* d_out, int out_size, void* d_ws, size_t ws_size,
                              hipStream_t stream) {
  const float* x    = (const float*)d_in[0];
  const float* Wx   = (const float*)d_in[1];
  const float* Wh   = (const float*)d_in[2];
  const float* bias = (const float*)d_in[3];
  float* out = (float*)d_out;

  char* ws   = (char*)d_ws;
  short* wT  = (short*)(ws + WT_OFF);
  short* h0  = (short*)(ws + H0_OFF);
  short* h1  = (short*)(ws + H1_OFF);
  int* flags = (int*)(ws + FLAGS_OFF);
  short* xP  = (short*)(ws + XB_OFF);

  const bool xbf16 = (ws_size >= (size_t)WS_NEED_FULL);

  hipLaunchKernelGGL(prep_weights, dim3(16384), dim3(256), 0, stream, Wx, Wh, wT, flags);
  if (xbf16) {
    hipLaunchKernelGGL(prep_x, dim3(65536), dim3(256), 0, stream, x, xP);
    hipLaunchKernelGGL((lstm_persist<true>), dim3(128), dim3(256), 0, stream,
                       x, xP, wT, bias, h0, h1, flags, out);
  } else {
    hipLaunchKernelGGL((lstm_persist<false>), dim3(128), dim3(256), 0, stream,
                       x, xP, wT, bias, h0, h1, flags, out);
  }
}